// Round 2
// baseline (175.752 us; speedup 1.0000x reference)
//
#include <hip/hip_runtime.h>
#include <hip/hip_bf16.h>

// GCK 3x3 conv == plain 3x3 conv with W_eff = basis · linCombs.
// Implemented as implicit GEMM: M=O=64, N=512*512, K=64*9=576, bf16 MFMA.
// K ordering: k = tap*64 + c  (tap = 3r+s) -> each K=32 MFMA slice has ONE tap,
// so B-fragments are contiguous channels-last loads at a shifted pixel.

constexpr int kC = 64, kO = 64;
constexpr int kH = 514, kW = 514;
constexpr int kHO = 512, kWO = 512;
constexpr int kNPIX = kH * kW;          // 264196

typedef __attribute__((ext_vector_type(8))) short short8;    // 8 bf16 (4 VGPRs)
typedef __attribute__((ext_vector_type(4))) float floatx4;   // 4 fp32 acc

__device__ inline unsigned short f2bf(float f) {
    unsigned int u = __float_as_uint(f);
    unsigned int r = (u + 0x7fffu + ((u >> 16) & 1u)) >> 16;  // RN-even
    return (unsigned short)r;
}

// ---------------------------------------------------------------- weight prep
// W_eff[o,c,3r+s] = sum_{i,j} lin[o, c*9+3i+j] * V[i,r]*V[j,s]
// stored pre-swizzled into MFMA A-fragment order:
//   kglob = tap*64 + c ; ks = kglob>>5 ; kg = (kglob>>3)&3 ; e = kglob&7
//   w2[ ((ks*4+kg)*64 + o)*8 + e ] = bf16(W_eff)
__global__ void gck_wprep(const float* __restrict__ lin, unsigned short* __restrict__ w2) {
    int t = blockIdx.x * 256 + threadIdx.x;
    if (t >= kO * kC * 9) return;
    int tap = t % 9;
    int c   = (t / 9) % kC;
    int o   = t / (9 * kC);
    int r = tap / 3, s = tap % 3;
    const float Vm[3][3] = {{1.f, 1.f, 1.f}, {1.f, -1.f, 1.f}, {1.f, 1.f, -1.f}};
    float acc = 0.f;
#pragma unroll
    for (int i = 0; i < 3; i++)
#pragma unroll
        for (int j = 0; j < 3; j++)
            acc += lin[o * (kC * 9) + c * 9 + 3 * i + j] * Vm[i][r] * Vm[j][s];
    int kglob = tap * 64 + c;
    int ks = kglob >> 5, kg = (kglob >> 3) & 3, e = kglob & 7;
    w2[((ks * 4 + kg) * 64 + o) * 8 + e] = f2bf(acc);
}

// ------------------------------------------------- fp32 CHW -> bf16 (HW)C
__global__ __launch_bounds__(256) void gck_xpose(const float* __restrict__ x,
                                                 unsigned short* __restrict__ xt) {
    __shared__ float lds[64][65];
    int pbase = blockIdx.x * 64;
    int t = threadIdx.x;
    int po = t & 63;
    int p = pbase + po;
    bool pv = p < kNPIX;
#pragma unroll
    for (int i = 0; i < 16; i++) {
        int ch = i * 4 + (t >> 6);
        lds[ch][po] = pv ? x[ch * kNPIX + p] : 0.f;
    }
    __syncthreads();
#pragma unroll
    for (int i = 0; i < 4; i++) {
        int pix = i * 16 + (t >> 4);
        int pg = pbase + pix;
        if (pg < kNPIX) {
            int c4 = (t & 15) * 4;
            ushort4 v;
            v.x = f2bf(lds[c4 + 0][pix]);
            v.y = f2bf(lds[c4 + 1][pix]);
            v.z = f2bf(lds[c4 + 2][pix]);
            v.w = f2bf(lds[c4 + 3][pix]);
            *reinterpret_cast<ushort4*>(&xt[pg * 64 + c4]) = v;
        }
    }
}

// ------------------------------------------------------------ implicit GEMM
// block = 4 waves, one output row h, 256 pixels (seg of 2 per row).
// wave: 64 o x 64 pixels, acc 4x4 fragments of 16x16, K-loop of 18 slices.
__global__ __launch_bounds__(256) void gck_gemm(const unsigned short* __restrict__ xt,
                                                const unsigned short* __restrict__ w2,
                                                float* __restrict__ out) {
    int bid = blockIdx.x;       // 0..1023
    int h   = bid >> 1;
    int seg = bid & 1;
    int wave = threadIdx.x >> 6;
    int lane = threadIdx.x & 63;
    int l16  = lane & 15;
    int kg   = lane >> 4;
    int wbase = seg * 256 + wave * 64;

    floatx4 acc[4][4];
#pragma unroll
    for (int m = 0; m < 4; m++)
#pragma unroll
        for (int n = 0; n < 4; n++) acc[m][n] = (floatx4){0.f, 0.f, 0.f, 0.f};

    const short8* w2v = reinterpret_cast<const short8*>(w2);

#pragma unroll
    for (int ks = 0; ks < 18; ks++) {
        int tap = ks >> 1;
        int r = tap / 3;
        int s = tap - r * 3;

        // A fragments: o = m*16 + l16, k-group kg
        short8 a[4];
        const short8* wp = w2v + (ks * 4 + kg) * 64 + l16;
#pragma unroll
        for (int m = 0; m < 4; m++) a[m] = wp[m * 16];

        // B fragments: pixel = (h+r)*kW + (wbase + n*16 + l16 + s), ch base
        int rowb = (h + r) * kW;
        int cb = (ks & 1) * 32 + kg * 8;
        short8 b[4];
#pragma unroll
        for (int n = 0; n < 4; n++) {
            int wx = wbase + n * 16 + l16 + s;
            b[n] = *reinterpret_cast<const short8*>(&xt[(rowb + wx) * 64 + cb]);
        }

#pragma unroll
        for (int m = 0; m < 4; m++)
#pragma unroll
            for (int n = 0; n < 4; n++)
                acc[m][n] = __builtin_amdgcn_mfma_f32_16x16x32_bf16(a[m], b[n], acc[m][n], 0, 0, 0);
    }

    // epilogue: D row = m*16 + kg*4 + j (o), col = wbase + n*16 + l16 (w)
#pragma unroll
    for (int m = 0; m < 4; m++) {
#pragma unroll
        for (int n = 0; n < 4; n++) {
            int wcol = wbase + n * 16 + l16;
#pragma unroll
            for (int j = 0; j < 4; j++) {
                int o = m * 16 + kg * 4 + j;
                out[(o * kHO + h) * kWO + wcol] = acc[m][n][j];
            }
        }
    }
}

extern "C" void kernel_launch(void* const* d_in, const int* in_sizes, int n_in,
                              void* d_out, int out_size, void* d_ws, size_t ws_size,
                              hipStream_t stream) {
    const float* x   = (const float*)d_in[0];   // (1,64,514,514) fp32
    const float* lin = (const float*)d_in[1];   // (64,576) fp32
    float* out = (float*)d_out;                 // (1,64,512,512) fp32

    unsigned short* w2 = (unsigned short*)d_ws;                       // 72 KiB
    unsigned short* xt = (unsigned short*)((char*)d_ws + (1 << 20));  // 33.8 MiB

    gck_wprep<<<(kO * kC * 9 + 255) / 256, 256, 0, stream>>>(lin, w2);
    gck_xpose<<<(kNPIX + 63) / 64, 256, 0, stream>>>(x, xt);
    gck_gemm<<<kHO * 2, 256, 0, stream>>>(xt, w2, out);
}

// Round 4
// 142.177 us; speedup vs baseline: 1.2361x; 1.2361x over previous
//
#include <hip/hip_runtime.h>
#include <hip/hip_bf16.h>

// GCK 3x3 conv == plain 3x3 conv with W_eff = basis · linCombs.
// FUSED implicit GEMM: M=O=64, N=512*512, K=C*9=576, bf16 MFMA 16x16x32.
// Each block: stage 6x66x64ch input tile in LDS (fp32 CHW -> bf16 channels-last,
// XOR-swizzled 16B units so ds_read_b128 B-fragments are bank-conflict-free),
// then K-loop of 18 slices (k = tap*64 + c), 4 waves x (1 row x 64 px x 64 o).

constexpr int kC = 64, kO = 64;
constexpr int kH = 514, kW = 514;
constexpr int kHO = 512, kWO = 512;
constexpr int kNPIX = kH * kW;          // 264196

typedef __attribute__((ext_vector_type(8))) short short8;    // 8 bf16
typedef __attribute__((ext_vector_type(4))) float floatx4;   // 4 fp32 acc

__device__ inline unsigned short f2bf(float f) {
    unsigned int u = __float_as_uint(f);
    unsigned int r = (u + 0x7fffu + ((u >> 16) & 1u)) >> 16;  // RN-even
    return (unsigned short)r;
}

// ---------------------------------------------------------------- weight prep
// W_eff[o,c,3r+s] = sum_{i,j} lin[o, c*9+3i+j] * V[i,r]*V[j,s]
// stored pre-swizzled into MFMA A-fragment order:
//   kglob = tap*64 + c ; ks = kglob>>5 ; kg = (kglob>>3)&3 ; e = kglob&7
//   w2[ ((ks*4+kg)*64 + o)*8 + e ] = bf16(W_eff)
__global__ void gck_wprep(const float* __restrict__ lin, unsigned short* __restrict__ w2) {
    int t = blockIdx.x * 256 + threadIdx.x;
    if (t >= kO * kC * 9) return;
    int tap = t % 9;
    int c   = (t / 9) % kC;
    int o   = t / (9 * kC);
    int r = tap / 3, s = tap % 3;
    const float Vm[3][3] = {{1.f, 1.f, 1.f}, {1.f, -1.f, 1.f}, {1.f, 1.f, -1.f}};
    float acc = 0.f;
#pragma unroll
    for (int i = 0; i < 3; i++)
#pragma unroll
        for (int j = 0; j < 3; j++)
            acc += lin[o * (kC * 9) + c * 9 + 3 * i + j] * Vm[i][r] * Vm[j][s];
    int kglob = tap * 64 + c;
    int ks = kglob >> 5, kg = (kglob >> 3) & 3, e = kglob & 7;
    w2[((ks * 4 + kg) * 64 + o) * 8 + e] = f2bf(acc);
}

// ------------------------------------------------------------- fused conv
// grid: 1024 blocks = 128 row-tiles (4 output rows) x 8 col-tiles (64 px).
// bid = rt*8 + ct  -> vertical neighbors (rt+-1) share XCD (bid%8) for halo L2 reuse.
// LDS: xs[r 0..5][col 0..65][64 ch] bf16; 16B channel-unit u stored at u^(col&7).
__global__ __launch_bounds__(256, 3) void gck_conv(const float* __restrict__ x,
                                                   const unsigned short* __restrict__ w2,
                                                   float* __restrict__ out) {
    __shared__ unsigned short xs[6 * 66 * 64];   // 49.5 KiB -> 3 blocks/CU

    const int bid = blockIdx.x;
    const int ct = bid & 7;
    const int rt = bid >> 3;
    const int hbase = rt * 4;
    const int wbase = ct * 64;
    const int t    = threadIdx.x;
    const int wave = t >> 6;
    const int lane = t & 63;
    const int l16  = lane & 15;
    const int kg   = lane >> 4;

    // ---- stage: fp32 CHW -> bf16 (row, col, ch) with XOR-swizzled 16B units
    {
        const int w0 = lane;      // col 0..63
#pragma unroll
        for (int p = 0; p < 24; ++p) {
            int idx = p * 4 + wave;            // 0..95 = (r, cgrp)
            int r   = idx >> 4;
            int cg  = idx & 15;
            int ch0 = cg * 4;
            const float* gp = x + (hbase + r) * kW + wbase + w0;
            float f0 = gp[(ch0 + 0) * kNPIX];
            float f1 = gp[(ch0 + 1) * kNPIX];
            float f2 = gp[(ch0 + 2) * kNPIX];
            float f3 = gp[(ch0 + 3) * kNPIX];
            ushort4 v;
            v.x = f2bf(f0); v.y = f2bf(f1); v.z = f2bf(f2); v.w = f2bf(f3);
            int addr = (r * 66 + w0) * 64 + ((cg >> 1) ^ (w0 & 7)) * 8 + (cg & 1) * 4;
            *reinterpret_cast<ushort4*>(&xs[addr]) = v;
        }
        // edge cols 64,65 : 6 rows x 64 ch x 2 cols = 768 elements
#pragma unroll
        for (int j = 0; j < 3; ++j) {
            int idx = j * 256 + t;             // 0..767
            int col = 64 + (idx & 1);
            int ch  = (idx >> 1) & 63;
            int r   = idx >> 7;
            float f = x[ch * kNPIX + (hbase + r) * kW + wbase + col];
            int addr = (r * 66 + col) * 64 + ((ch >> 3) ^ (col & 7)) * 8 + (ch & 7);
            xs[addr] = f2bf(f);
        }
    }
    __syncthreads();

    floatx4 acc[4][4];
#pragma unroll
    for (int m = 0; m < 4; m++)
#pragma unroll
        for (int n = 0; n < 4; n++) acc[m][n] = (floatx4){0.f, 0.f, 0.f, 0.f};

    const short8* w2v = reinterpret_cast<const short8*>(w2);

    // A prefetch (global, L2-resident 72 KiB)
    short8 a_cur[4];
#pragma unroll
    for (int m = 0; m < 4; m++) a_cur[m] = w2v[(0 * 4 + kg) * 64 + m * 16 + l16];

#pragma unroll 2
    for (int ks = 0; ks < 18; ++ks) {
        int tap = ks >> 1;
        int r0  = tap / 3;
        int s   = tap - r0 * 3;

        short8 a_nxt[4];
        int ksn = (ks < 17) ? ks + 1 : ks;
#pragma unroll
        for (int m = 0; m < 4; m++) a_nxt[m] = w2v[(ksn * 4 + kg) * 64 + m * 16 + l16];

        int rr = wave + r0;                    // tile row 0..5
        int u  = (ks & 1) * 4 + kg;            // 16B unit 0..7
        short8 b[4];
#pragma unroll
        for (int n = 0; n < 4; ++n) {
            int col  = n * 16 + l16 + s;       // 0..65
            int addr = (rr * 66 + col) * 64 + ((u ^ (col & 7)) * 8);
            b[n] = *reinterpret_cast<const short8*>(&xs[addr]);
        }

#pragma unroll
        for (int m = 0; m < 4; m++)
#pragma unroll
            for (int n = 0; n < 4; n++)
                acc[m][n] = __builtin_amdgcn_mfma_f32_16x16x32_bf16(a_cur[m], b[n], acc[m][n], 0, 0, 0);

#pragma unroll
        for (int m = 0; m < 4; m++) a_cur[m] = a_nxt[m];
    }

    // epilogue: D row = m*16 + kg*4 + j (o), col = wbase + n*16 + l16 (w)
    const int h = hbase + wave;
#pragma unroll
    for (int m = 0; m < 4; m++) {
#pragma unroll
        for (int n = 0; n < 4; n++) {
            int wcol = wbase + n * 16 + l16;
#pragma unroll
            for (int j = 0; j < 4; j++) {
                int o = m * 16 + kg * 4 + j;
                out[(o * kHO + h) * kWO + wcol] = acc[m][n][j];
            }
        }
    }
}

extern "C" void kernel_launch(void* const* d_in, const int* in_sizes, int n_in,
                              void* d_out, int out_size, void* d_ws, size_t ws_size,
                              hipStream_t stream) {
    const float* x   = (const float*)d_in[0];   // (1,64,514,514) fp32
    const float* lin = (const float*)d_in[1];   // (64,576) fp32
    float* out = (float*)d_out;                 // (1,64,512,512) fp32

    unsigned short* w2 = (unsigned short*)d_ws; // 72 KiB

    gck_wprep<<<(kO * kC * 9 + 255) / 256, 256, 0, stream>>>(lin, w2);
    gck_conv<<<(kHO / 4) * 8, 256, 0, stream>>>(x, w2, out);
}

// Round 5
// 138.738 us; speedup vs baseline: 1.2668x; 1.0248x over previous
//
#include <hip/hip_runtime.h>
#include <hip/hip_bf16.h>

// GCK 3x3 conv == plain 3x3 conv with W_eff = basis · linCombs.
// FUSED implicit GEMM: M=O=64, N=512*512, K=C*9=576, bf16 MFMA 16x16x32.
// Each block: stage 6x66x64ch input tile in LDS (fp32 CHW -> bf16 channels-last,
// XOR-swizzled 16B units so ds_read_b128 B-fragments hit the 8-cycle floor),
// then K-loop of 18 slices (k = tap*64 + c), 4 waves x (1 row x 64 px x 64 o).
// Staging uses float4 (even rows) / 2x float2 (odd rows, 8B-aligned only since
// kW=514) -> 36 VMEM instrs/thread instead of 96 scalar dwords.

constexpr int kC = 64, kO = 64;
constexpr int kH = 514, kW = 514;
constexpr int kHO = 512, kWO = 512;
constexpr int kNPIX = kH * kW;          // 264196

typedef __attribute__((ext_vector_type(8))) short short8;    // 8 bf16
typedef __attribute__((ext_vector_type(4))) float floatx4;   // 4 fp32 acc

__device__ inline unsigned short f2bf(float f) {
    unsigned int u = __float_as_uint(f);
    unsigned int r = (u + 0x7fffu + ((u >> 16) & 1u)) >> 16;  // RN-even
    return (unsigned short)r;
}

// ---------------------------------------------------------------- weight prep
// W_eff[o,c,3r+s] = sum_{i,j} lin[o, c*9+3i+j] * V[i,r]*V[j,s]
// stored pre-swizzled into MFMA A-fragment order:
//   kglob = tap*64 + c ; ks = kglob>>5 ; kg = (kglob>>3)&3 ; e = kglob&7
//   w2[ ((ks*4+kg)*64 + o)*8 + e ] = bf16(W_eff)
__global__ void gck_wprep(const float* __restrict__ lin, unsigned short* __restrict__ w2) {
    int t = blockIdx.x * 256 + threadIdx.x;
    if (t >= kO * kC * 9) return;
    int tap = t % 9;
    int c   = (t / 9) % kC;
    int o   = t / (9 * kC);
    int r = tap / 3, s = tap % 3;
    const float Vm[3][3] = {{1.f, 1.f, 1.f}, {1.f, -1.f, 1.f}, {1.f, 1.f, -1.f}};
    float acc = 0.f;
#pragma unroll
    for (int i = 0; i < 3; i++)
#pragma unroll
        for (int j = 0; j < 3; j++)
            acc += lin[o * (kC * 9) + c * 9 + 3 * i + j] * Vm[i][r] * Vm[j][s];
    int kglob = tap * 64 + c;
    int ks = kglob >> 5, kg = (kglob >> 3) & 3, e = kglob & 7;
    w2[((ks * 4 + kg) * 64 + o) * 8 + e] = f2bf(acc);
}

// ------------------------------------------------------------- fused conv
// grid: 1024 blocks = 128 row-tiles (4 output rows) x 8 col-tiles (64 px).
// bid = rt*8 + ct -> vertical neighbors (rt+-1) share XCD (bid%8) for halo L2 reuse.
// LDS: xs[r 0..5][col 0..65][64 ch] bf16; 16B channel-unit u stored at u^(col&7).
__global__ __launch_bounds__(256, 3) void gck_conv(const float* __restrict__ x,
                                                   const unsigned short* __restrict__ w2,
                                                   float* __restrict__ out) {
    __shared__ unsigned short xs[6 * 66 * 64];   // 49.5 KiB -> 3 blocks/CU

    const int bid = blockIdx.x;
    const int ct = bid & 7;
    const int rt = bid >> 3;
    const int hbase = rt * 4;
    const int wbase = ct * 64;
    const int t    = threadIdx.x;
    const int wave = t >> 6;
    const int lane = t & 63;
    const int l16  = lane & 15;
    const int kg   = lane >> 4;

    // ---- stage: fp32 CHW -> bf16 (row, col, ch), XOR-swizzled 16B units.
    // thread t: col-quad q = t&15 (cols 4q..4q+3), ch-group cg4 = t>>4 (ch 4*cg4..+3)
    {
        const int q    = t & 15;
        const int cg4  = t >> 4;
        const int ch0  = cg4 * 4;
        const int colb = q * 4;
#pragma unroll
        for (int r = 0; r < 6; ++r) {
            const float* gp = x + (hbase + r) * kW + wbase + colb;
            float v[4][4];                       // [c][j] : ch x col
            if ((r & 1) == 0) {                  // row offset 16B-aligned
#pragma unroll
                for (int c = 0; c < 4; ++c) {
                    float4 f = *reinterpret_cast<const float4*>(gp + (ch0 + c) * kNPIX);
                    v[c][0] = f.x; v[c][1] = f.y; v[c][2] = f.z; v[c][3] = f.w;
                }
            } else {                             // odd row: only 8B-aligned (kW=514)
#pragma unroll
                for (int c = 0; c < 4; ++c) {
                    float2 f0 = *reinterpret_cast<const float2*>(gp + (ch0 + c) * kNPIX);
                    float2 f1 = *reinterpret_cast<const float2*>(gp + (ch0 + c) * kNPIX + 2);
                    v[c][0] = f0.x; v[c][1] = f0.y; v[c][2] = f1.x; v[c][3] = f1.y;
                }
            }
#pragma unroll
            for (int j = 0; j < 4; ++j) {
                int col = colb + j;
                ushort4 u4;
                u4.x = f2bf(v[0][j]); u4.y = f2bf(v[1][j]);
                u4.z = f2bf(v[2][j]); u4.w = f2bf(v[3][j]);
                int addr = (r * 66 + col) * 64 + (((cg4 >> 1) ^ (col & 7)) * 8) + (cg4 & 1) * 4;
                *reinterpret_cast<ushort4*>(&xs[addr]) = u4;
            }
        }
        // edge cols 64,65 : 6 rows x 64 ch x 2 cols = 768 elements
#pragma unroll
        for (int j = 0; j < 3; ++j) {
            int idx = j * 256 + t;               // 0..767
            int col = 64 + (idx & 1);
            int ch  = (idx >> 1) & 63;
            int r   = idx >> 7;
            float f = x[ch * kNPIX + (hbase + r) * kW + wbase + col];
            int addr = (r * 66 + col) * 64 + ((ch >> 3) ^ (col & 7)) * 8 + (ch & 7);
            xs[addr] = f2bf(f);
        }
    }
    __syncthreads();

    floatx4 acc[4][4];
#pragma unroll
    for (int m = 0; m < 4; m++)
#pragma unroll
        for (int n = 0; n < 4; n++) acc[m][n] = (floatx4){0.f, 0.f, 0.f, 0.f};

    const short8* w2v = reinterpret_cast<const short8*>(w2);

    // A prefetch (global, L2-resident 72 KiB)
    short8 a_cur[4];
#pragma unroll
    for (int m = 0; m < 4; m++) a_cur[m] = w2v[(0 * 4 + kg) * 64 + m * 16 + l16];

#pragma unroll 2
    for (int ks = 0; ks < 18; ++ks) {
        int tap = ks >> 1;
        int r0  = tap / 3;
        int s   = tap - r0 * 3;

        short8 a_nxt[4];
        int ksn = (ks < 17) ? ks + 1 : ks;
#pragma unroll
        for (int m = 0; m < 4; m++) a_nxt[m] = w2v[(ksn * 4 + kg) * 64 + m * 16 + l16];

        int rr = wave + r0;                    // tile row 0..5
        int u  = (ks & 1) * 4 + kg;            // 16B unit 0..7
        short8 b[4];
#pragma unroll
        for (int n = 0; n < 4; ++n) {
            int col  = n * 16 + l16 + s;       // 0..65
            int addr = (rr * 66 + col) * 64 + ((u ^ (col & 7)) * 8);
            b[n] = *reinterpret_cast<const short8*>(&xs[addr]);
        }

#pragma unroll
        for (int m = 0; m < 4; m++)
#pragma unroll
            for (int n = 0; n < 4; n++)
                acc[m][n] = __builtin_amdgcn_mfma_f32_16x16x32_bf16(a_cur[m], b[n], acc[m][n], 0, 0, 0);

#pragma unroll
        for (int m = 0; m < 4; m++) a_cur[m] = a_nxt[m];
    }

    // epilogue: D row = m*16 + kg*4 + j (o), col = wbase + n*16 + l16 (w)
    const int h = hbase + wave;
#pragma unroll
    for (int m = 0; m < 4; m++) {
#pragma unroll
        for (int n = 0; n < 4; n++) {
            int wcol = wbase + n * 16 + l16;
#pragma unroll
            for (int j = 0; j < 4; j++) {
                int o = m * 16 + kg * 4 + j;
                out[(o * kHO + h) * kWO + wcol] = acc[m][n][j];
            }
        }
    }
}

extern "C" void kernel_launch(void* const* d_in, const int* in_sizes, int n_in,
                              void* d_out, int out_size, void* d_ws, size_t ws_size,
                              hipStream_t stream) {
    const float* x   = (const float*)d_in[0];   // (1,64,514,514) fp32
    const float* lin = (const float*)d_in[1];   // (64,576) fp32
    float* out = (float*)d_out;                 // (1,64,512,512) fp32

    unsigned short* w2 = (unsigned short*)d_ws; // 72 KiB

    gck_wprep<<<(kO * kC * 9 + 255) / 256, 256, 0, stream>>>(lin, w2);
    gck_conv<<<(kHO / 4) * 8, 256, 0, stream>>>(x, w2, out);
}